// Round 1
// baseline (5427.743 us; speedup 1.0000x reference)
//
#include <hip/hip_runtime.h>
#include <cstdint>
#include <cstddef>

#define B_ 2
#define S_ 1024
#define D_ 1024
#define H_ 16
#define DK_ 64
#define F_ 4096
#define L_ 4
#define M_ (B_*S_)   // 2048

// ---------------- block reductions (256 threads = 4 waves of 64) -------------
__device__ __forceinline__ float blockSum256(float v) {
  __shared__ float sh[4];
  #pragma unroll
  for (int o = 32; o > 0; o >>= 1) v += __shfl_down(v, o);
  __syncthreads();                       // protect sh from a previous call
  if ((threadIdx.x & 63) == 0) sh[threadIdx.x >> 6] = v;
  __syncthreads();
  return sh[0] + sh[1] + sh[2] + sh[3];
}

__device__ __forceinline__ float blockMax256(float v) {
  __shared__ float sh[4];
  #pragma unroll
  for (int o = 32; o > 0; o >>= 1) v = fmaxf(v, __shfl_down(v, o));
  __syncthreads();
  if ((threadIdx.x & 63) == 0) sh[threadIdx.x >> 6] = v;
  __syncthreads();
  return fmaxf(fmaxf(sh[0], sh[1]), fmaxf(sh[2], sh[3]));
}

// ---------------- embedding + sinusoidal PE ----------------------------------
__global__ void __launch_bounds__(256) embed_k(const int* __restrict__ ids,
                                               const float* __restrict__ emb,
                                               float* __restrict__ h) {
  size_t idx = (size_t)blockIdx.x * 256 + threadIdx.x;   // over M*D
  int m = (int)(idx >> 10);
  int d = (int)(idx & 1023);
  int s = m & (S_ - 1);            // m = b*S + s
  int id = ids[m];
  // div = exp((d&~1) * (-ln(10000)/D)); even d -> sin, odd d -> cos
  float div = expf((float)(d & ~1) * (-9.210340371976184f / 1024.0f));
  float ang = (float)s * div;
  float pe = (d & 1) ? cosf(ang) : sinf(ang);
  h[idx] = emb[(size_t)id * D_ + d] * 32.0f + pe;
}

// ---------------- generic GEMM: C[M,N] = A[M,K]@W[K,N] + bias (opt relu) -----
// tile 128x64, BK=16, 256 threads, 8x4 per thread
template <bool RELU>
__global__ void __launch_bounds__(256) gemm128x64(const float* __restrict__ A,
                                                  const float* __restrict__ W,
                                                  const float* __restrict__ bias,
                                                  float* __restrict__ C,
                                                  int M, int N, int K) {
  __shared__ __align__(16) float As[16][132];  // [k][m], 132%32=4 -> 2-way on write (free)
  __shared__ __align__(16) float Ws[16][68];   // [k][n]
  const int tid  = threadIdx.x;
  const int row0 = blockIdx.y << 7;
  const int col0 = blockIdx.x << 6;
  const int tr = (tid >> 4) << 3;   // 0..120
  const int tc = (tid & 15) << 2;   // 0..60
  float acc[8][4];
  #pragma unroll
  for (int i = 0; i < 8; ++i)
    #pragma unroll
    for (int j = 0; j < 4; ++j) acc[i][j] = 0.0f;

  for (int k0 = 0; k0 < K; k0 += 16) {
    #pragma unroll
    for (int i = 0; i < 8; ++i) {      // A tile: 128x16
      int idx = tid + (i << 8);
      int m = idx >> 4, kk = idx & 15;
      As[kk][m] = A[(size_t)(row0 + m) * K + (k0 + kk)];
    }
    #pragma unroll
    for (int i = 0; i < 4; ++i) {      // W tile: 16x64
      int idx = tid + (i << 8);
      int kk = idx >> 6, n = idx & 63;
      Ws[kk][n] = W[(size_t)(k0 + kk) * N + (col0 + n)];
    }
    __syncthreads();
    #pragma unroll
    for (int kk = 0; kk < 16; ++kk) {
      float a[8], b[4];
      *(float4*)&a[0] = *(const float4*)&As[kk][tr];
      *(float4*)&a[4] = *(const float4*)&As[kk][tr + 4];
      *(float4*)&b[0] = *(const float4*)&Ws[kk][tc];
      #pragma unroll
      for (int i = 0; i < 8; ++i)
        #pragma unroll
        for (int j = 0; j < 4; ++j) acc[i][j] = fmaf(a[i], b[j], acc[i][j]);
    }
    __syncthreads();
  }
  #pragma unroll
  for (int i = 0; i < 8; ++i)
    #pragma unroll
    for (int j = 0; j < 4; ++j) {
      float v = acc[i][j] + bias[col0 + tc + j];
      if (RELU) v = fmaxf(v, 0.0f);
      C[(size_t)(row0 + tr + i) * N + (col0 + tc + j)] = v;
    }
}

// ---------------- attention scores: out = q @ k^T * scale (per b,h) ----------
// grid (S/64 j, S/64 i, B*H), block 256, 4x4/thread
__global__ void __launch_bounds__(256) attn_scores(const float* __restrict__ q,
                                                   const float* __restrict__ k,
                                                   float* __restrict__ o) {
  const int bh = blockIdx.z;
  const int b = bh >> 4, hh = bh & 15;
  const float* qb = q + ((size_t)b << 20) + (hh << 6);   // b*S*D + hh*64
  const float* kb = k + ((size_t)b << 20) + (hh << 6);
  float* ob = o + ((size_t)bh << 20);                    // bh*S*S
  const int i0 = blockIdx.y << 6, j0 = blockIdx.x << 6;
  __shared__ float Qs[64][65];     // [i][d]
  __shared__ float Kst[64][65];    // [d][j]  (transposed store, 2-way write, free)
  const int tid = threadIdx.x;
  #pragma unroll
  for (int it = 0; it < 16; ++it) {
    int idx = tid + (it << 8);
    int r = idx >> 6, c = idx & 63;
    Qs[r][c]  = qb[(size_t)(i0 + r) * 1024 + c];
    Kst[c][r] = kb[(size_t)(j0 + r) * 1024 + c];
  }
  __syncthreads();
  const int ti = (tid >> 4) << 2, tj = (tid & 15) << 2;
  float acc[4][4] = {};
  #pragma unroll 8
  for (int d = 0; d < 64; ++d) {
    float a[4], bb[4];
    #pragma unroll
    for (int i = 0; i < 4; ++i) a[i] = Qs[ti + i][d];
    #pragma unroll
    for (int j = 0; j < 4; ++j) bb[j] = Kst[d][tj + j];
    #pragma unroll
    for (int i = 0; i < 4; ++i)
      #pragma unroll
      for (int j = 0; j < 4; ++j) acc[i][j] = fmaf(a[i], bb[j], acc[i][j]);
  }
  #pragma unroll
  for (int i = 0; i < 4; ++i)
    #pragma unroll
    for (int j = 0; j < 4; ++j)
      ob[(size_t)(i0 + ti + i) * 1024 + (j0 + tj + j)] = acc[i][j] * 0.125f;
}

// ---------------- softmax over rows of 1024 (in-place) -----------------------
__global__ void __launch_bounds__(256) softmax_rows(float* __restrict__ a) {
  float4* p = reinterpret_cast<float4*>(a) + ((size_t)blockIdx.x << 8);
  const int t = threadIdx.x;
  float4 x = p[t];
  float mx = blockMax256(fmaxf(fmaxf(x.x, x.y), fmaxf(x.z, x.w)));
  x.x = expf(x.x - mx); x.y = expf(x.y - mx);
  x.z = expf(x.z - mx); x.w = expf(x.w - mx);
  float s = blockSum256(x.x + x.y + x.z + x.w);
  float inv = 1.0f / s;
  x.x *= inv; x.y *= inv; x.z *= inv; x.w *= inv;
  p[t] = x;
}

// ---------------- ctx = aw @ v (per b,h): [S,S]@[S,64] -----------------------
// grid (S/64 i, B*H), block 256, 4x4/thread
__global__ void __launch_bounds__(256) attn_ctx(const float* __restrict__ aw,
                                                const float* __restrict__ v,
                                                float* __restrict__ c) {
  const int bh = blockIdx.y, b = bh >> 4, hh = bh & 15;
  const float* A = aw + ((size_t)bh << 20);
  const float* V = v + ((size_t)b << 20) + (hh << 6);
  float* C = c + ((size_t)b << 20) + (hh << 6);
  const int i0 = blockIdx.x << 6;
  __shared__ __align__(16) float As[16][68];  // [k][i]
  __shared__ __align__(16) float Vs[16][68];  // [k][d]
  const int tid = threadIdx.x;
  const int ti = (tid >> 4) << 2, td = (tid & 15) << 2;
  float acc[4][4] = {};
  for (int k0 = 0; k0 < 1024; k0 += 16) {
    #pragma unroll
    for (int it = 0; it < 4; ++it) {     // A tile 64x16
      int idx = tid + (it << 8);
      int m = idx >> 4, kk = idx & 15;
      As[kk][m] = A[(size_t)(i0 + m) * 1024 + (k0 + kk)];
    }
    {
      int kk = tid >> 6, dd = tid & 63;  // V tile 16x64
      #pragma unroll
      for (int it = 0; it < 4; ++it)
        Vs[kk + (it << 2)][dd] = V[(size_t)(k0 + kk + (it << 2)) * 1024 + dd];
    }
    __syncthreads();
    #pragma unroll
    for (int kk = 0; kk < 16; ++kk) {
      float a[4], bb[4];
      #pragma unroll
      for (int i = 0; i < 4; ++i) a[i] = As[kk][ti + i];
      *(float4*)&bb[0] = *(const float4*)&Vs[kk][td];
      #pragma unroll
      for (int i = 0; i < 4; ++i)
        #pragma unroll
        for (int j = 0; j < 4; ++j) acc[i][j] = fmaf(a[i], bb[j], acc[i][j]);
    }
    __syncthreads();
  }
  #pragma unroll
  for (int i = 0; i < 4; ++i)
    #pragma unroll
    for (int j = 0; j < 4; ++j)
      C[(size_t)(i0 + ti + i) * 1024 + (td + j)] = acc[i][j];
}

// ---------------- h = LayerNorm(h + r) * g + b (rows of 1024) ----------------
__global__ void __launch_bounds__(256) add_ln(float* __restrict__ h,
                                              const float* __restrict__ r,
                                              const float* __restrict__ g,
                                              const float* __restrict__ bta) {
  const size_t row = blockIdx.x;
  const int t = threadIdx.x;
  float4* hp = reinterpret_cast<float4*>(h + (row << 10));
  const float4* rp = reinterpret_cast<const float4*>(r + (row << 10));
  float4 x = hp[t], y = rp[t];
  x.x += y.x; x.y += y.y; x.z += y.z; x.w += y.w;
  float s = blockSum256(x.x + x.y + x.z + x.w);
  float mu = s * (1.0f / 1024.0f);
  float dx = x.x - mu, dy = x.y - mu, dz = x.z - mu, dw = x.w - mu;
  float sq = blockSum256(dx * dx + dy * dy + dz * dz + dw * dw);
  float rs = rsqrtf(sq * (1.0f / 1024.0f) + 1e-5f);
  const float4 gg = reinterpret_cast<const float4*>(g)[t];
  const float4 bb = reinterpret_cast<const float4*>(bta)[t];
  float4 o;
  o.x = dx * rs * gg.x + bb.x;
  o.y = dy * rs * gg.y + bb.y;
  o.z = dz * rs * gg.z + bb.z;
  o.w = dw * rs * gg.w + bb.w;
  hp[t] = o;
}

// ---------------------------------------------------------------------------
extern "C" void kernel_launch(void* const* d_in, const int* in_sizes, int n_in,
                              void* d_out, int out_size, void* d_ws, size_t ws_size,
                              hipStream_t stream) {
  (void)in_sizes; (void)n_in; (void)out_size; (void)ws_size;
  const int*   ids = (const int*)d_in[0];
  const float* emb = (const float*)d_in[1];
  const float* Wq  = (const float*)d_in[2];
  const float* bq  = (const float*)d_in[3];
  const float* Wk  = (const float*)d_in[4];
  const float* bk  = (const float*)d_in[5];
  const float* Wv  = (const float*)d_in[6];
  const float* bv  = (const float*)d_in[7];
  const float* Wo  = (const float*)d_in[8];
  const float* bo  = (const float*)d_in[9];
  const float* W1  = (const float*)d_in[10];
  const float* b1  = (const float*)d_in[11];
  const float* W2  = (const float*)d_in[12];
  const float* b2  = (const float*)d_in[13];
  const float* g1  = (const float*)d_in[14];
  const float* be1 = (const float*)d_in[15];
  const float* g2  = (const float*)d_in[16];
  const float* be2 = (const float*)d_in[17];

  float* out   = (float*)d_out;
  float* h     = out;                       // [M,D] lives directly in d_out
  float* attn0 = out + (size_t)M_ * D_;     // [L,B,H,S,S]

  float* ws = (float*)d_ws;
  float* q  = ws;                           // [M,D]
  float* kk = q  + (size_t)M_ * D_;         // [M,D]
  float* vv = kk + (size_t)M_ * D_;         // [M,D]
  float* t1 = vv + (size_t)M_ * D_;         // [M,F]
  float* t2 = t1 + (size_t)M_ * F_;         // [M,D]

  embed_k<<<dim3(M_ * D_ / 256), 256, 0, stream>>>(ids, emb, h);

  const dim3 g_nd(D_ / 64, M_ / 128);       // N=1024 GEMMs
  const dim3 g_nf(F_ / 64, M_ / 128);       // N=4096 GEMM
  for (int l = 0; l < L_; ++l) {
    const float* wq = Wq + (size_t)l * D_ * D_;
    const float* wk = Wk + (size_t)l * D_ * D_;
    const float* wv = Wv + (size_t)l * D_ * D_;
    const float* wo = Wo + (size_t)l * D_ * D_;
    const float* w1 = W1 + (size_t)l * D_ * F_;
    const float* w2 = W2 + (size_t)l * F_ * D_;
    float* attn_l = attn0 + (size_t)l * B_ * H_ * S_ * S_;

    gemm128x64<false><<<g_nd, 256, 0, stream>>>(h, wq, bq + l * D_, q,  M_, D_, D_);
    gemm128x64<false><<<g_nd, 256, 0, stream>>>(h, wk, bk + l * D_, kk, M_, D_, D_);
    gemm128x64<false><<<g_nd, 256, 0, stream>>>(h, wv, bv + l * D_, vv, M_, D_, D_);

    attn_scores<<<dim3(16, 16, 32), 256, 0, stream>>>(q, kk, attn_l);
    softmax_rows<<<dim3(B_ * H_ * S_), 256, 0, stream>>>(attn_l);
    attn_ctx<<<dim3(16, 32), 256, 0, stream>>>(attn_l, vv, t2);

    gemm128x64<false><<<g_nd, 256, 0, stream>>>(t2, wo, bo + l * D_, t1, M_, D_, D_);
    add_ln<<<dim3(M_), 256, 0, stream>>>(h, t1, g1 + l * D_, be1 + l * D_);

    gemm128x64<true ><<<g_nf, 256, 0, stream>>>(h,  w1, b1 + l * F_, t1, M_, F_, D_);
    gemm128x64<false><<<g_nd, 256, 0, stream>>>(t1, w2, b2 + l * D_, t2, M_, D_, F_);
    add_ln<<<dim3(M_), 256, 0, stream>>>(h, t2, g2 + l * D_, be2 + l * D_);
  }
}